// Round 4
// baseline (3085.409 us; speedup 1.0000x reference)
//
#include <hip/hip_runtime.h>

#define N_NODES 500000
#define N_EDGES 8000000
#define IN_DIM 128
#define H1 32
#define H2 16
#define NB_NODES 1954        // ceil(500000/256) = fine buckets of 256 nodes
#define NFINE 1954
#define NCOARSE 62           // node>>13 -> 0..61
#define CAPA 200             // stage capacity, coarse multisplit (chunk 8192, mean 132)
#define CAPB 340             // stage capacity, fine multisplit (chunk 8192/32 buckets, mean 256)

static __device__ __forceinline__ float bf2f(unsigned short u) {
    return __uint_as_float(((unsigned int)u) << 16);
}
static __device__ __forceinline__ unsigned short f2bf(float f) {
    unsigned int u = __float_as_uint(f);
    unsigned int r = (u + 0x7fffu + ((u >> 16) & 1u)) >> 16;
    return (unsigned short)r;
}
static __device__ __forceinline__ unsigned pack2bf(float a, float b) {
    return (unsigned)f2bf(a) | ((unsigned)f2bf(b) << 16);
}
static __device__ __forceinline__ float ldf(const void* p, int i, bool isf32) {
    return isf32 ? ((const float*)p)[i] : bf2f(((const unsigned short*)p)[i]);
}

// ---- dtype sniffer: low 16 bits of fp32 mantissas decode to wild bf16s ----
__global__ __launch_bounds__(64) void k_sniff(const unsigned int* __restrict__ x,
                                              int* __restrict__ flag) {
    int bad = 0;
    for (int i = threadIdx.x; i < 1024; i += 64) {
        float v = __uint_as_float((x[i] & 0xffffu) << 16);
        if (!(fabsf(v) < 1e6f)) bad = 1;
    }
    unsigned long long m = __ballot(bad);
    if (threadIdx.x == 0) *flag = (m != 0ull) ? 1 : 0;
}

// ---- node in-degree histogram ----
__global__ __launch_bounds__(256) void k_hist(const int* __restrict__ dst,
                                              int* __restrict__ cnt) {
    int i = blockIdx.x * blockDim.x + threadIdx.x;
    int stride = gridDim.x * blockDim.x;
    for (int e = i; e < N_EDGES; e += stride) {
        unsigned d = (unsigned)dst[e];
        if (d < N_NODES) atomicAdd(&cnt[d], 1);
    }
}

// ---- fine-bucket histogram: fhist[b] = sum cnt[b*256 .. b*256+255] ----
__global__ __launch_bounds__(256) void k_fhist(const int* __restrict__ cnt,
                                               int* __restrict__ fhist) {
    __shared__ int red[256];
    int tid = threadIdx.x;
    red[tid] = cnt[blockIdx.x * 256 + tid];   // cnt sized/zeroed to 500224
    __syncthreads();
    for (int o = 128; o > 0; o >>= 1) {
        if (tid < o) red[tid] += red[tid + o];
        __syncthreads();
    }
    if (tid == 0) fhist[blockIdx.x] = red[0];
}

// ---- single-block exclusive scan over 1954 fine buckets; emits cursors ----
__global__ __launch_bounds__(256) void k_scanf(const int* __restrict__ fhist,
                                               int* __restrict__ fbase,
                                               int* __restrict__ bcur,
                                               int* __restrict__ acur) {
    __shared__ int tmp[256];
    __shared__ int s_run;
    int tid = threadIdx.x;
    if (tid == 0) s_run = 0;
    __syncthreads();
    for (int base = 0; base < 2048; base += 256) {
        int i = base + tid;
        int v = (i < NFINE) ? fhist[i] : 0;
        int val = v;
        tmp[tid] = val;
        __syncthreads();
        for (int o = 1; o < 256; o <<= 1) {
            int t = (tid >= o) ? tmp[tid - o] : 0;
            __syncthreads();
            val += t;
            tmp[tid] = val;
            __syncthreads();
        }
        int run = s_run;
        if (i < NFINE) {
            int ex = run + val - v;
            fbase[i] = ex;
            bcur[i] = ex;
            if ((i & 31) == 0) acur[i >> 5] = ex;  // coarse cursor = fine boundary
        }
        __syncthreads();
        if (tid == 255) s_run = run + val;
        __syncthreads();
    }
    if (tid == 0) fbase[NFINE] = s_run;
}

// ---- dinv = rsqrt(deg+1) ----
__global__ __launch_bounds__(256) void k_dinv(const int* __restrict__ cnt,
                                              float* __restrict__ dinv) {
    int i = blockIdx.x * 256 + threadIdx.x;
    if (i < N_NODES) dinv[i] = rsqrtf((float)cnt[i] + 1.0f);
}

// ---- multisplit level A: raw edges -> 62 coarse buckets, 4B packed entries ----
// entry = (dst_local13 << 19) | src
__global__ __launch_bounds__(256) void k_scatA(const int* __restrict__ src,
                                               const int* __restrict__ dst,
                                               int* __restrict__ acur,
                                               unsigned* __restrict__ ebufA) {
    __shared__ unsigned stage[NCOARSE * CAPA];   // 49.6 KB
    __shared__ int lcnt[NCOARSE], nn[NCOARSE], soff[NCOARSE], sbase[NCOARSE];
    __shared__ int stot;
    int tid = threadIdx.x;
    int cb = blockIdx.x * 8192;                  // 977 blocks, one chunk each
    if (tid < NCOARSE) lcnt[tid] = 0;
    __syncthreads();
    for (int i = 0; i < 32; ++i) {
        int e = cb + (i << 8) + tid;
        if (e < N_EDGES) {
            unsigned d = (unsigned)dst[e], s = (unsigned)src[e];
            if (d < N_NODES) {                   // match k_hist's guard exactly
                unsigned b = d >> 13;
                unsigned p = ((d & 8191u) << 19) | s;
                int pos = atomicAdd(&lcnt[b], 1);
                if (pos < CAPA) stage[b * CAPA + pos] = p;
                else { int slot = atomicAdd(&acur[b], 1); ebufA[slot] = p; }
            }
        }
    }
    __syncthreads();
    if (tid < NCOARSE) nn[tid] = min(lcnt[tid], CAPA);
    __syncthreads();
    if (tid == 0) {
        int r = 0;
        for (int b = 0; b < NCOARSE; ++b) { soff[b] = r; r += nn[b]; }
        stot = r;
    }
    __syncthreads();
    if (tid < NCOARSE && nn[tid] > 0) sbase[tid] = atomicAdd(&acur[tid], nn[tid]);
    __syncthreads();
    for (int i = tid; i < stot; i += 256) {      // coalesced full-line flush
        int lo = 0, hi = NCOARSE - 1;
        while (lo < hi) { int mid = (lo + hi + 1) >> 1; if (soff[mid] <= i) lo = mid; else hi = mid - 1; }
        int r = i - soff[lo];
        ebufA[sbase[lo] + r] = stage[lo * CAPA + r];
    }
}

// ---- multisplit level B: coarse bucket -> 32 fine buckets (256 nodes each) ----
// entry out = (dst_local8 << 19) | src
__global__ __launch_bounds__(256) void k_scatB(const unsigned* __restrict__ ebufA,
                                               const int* __restrict__ fbase,
                                               int* __restrict__ bcur,
                                               unsigned* __restrict__ ebufB) {
    __shared__ unsigned stage[32 * CAPB];        // 43.5 KB
    __shared__ int lcnt[32], nn[32], soff[32], sbase[32];
    __shared__ int stot;
    int tid = threadIdx.x;
    int a = blockIdx.x >> 3, sub = blockIdx.x & 7;
    int f0 = a * 32;
    int lb = min(32, NFINE - f0);
    int abase = fbase[f0];
    int aend = fbase[min(f0 + 32, NFINE)];
    for (int cb = abase + sub * 8192; cb < aend; cb += 8 * 8192) {
        if (tid < 32) lcnt[tid] = 0;
        __syncthreads();
        for (int i = 0; i < 32; ++i) {
            int e = cb + (i << 8) + tid;
            if (e < aend) {
                unsigned p = ebufA[e];
                unsigned dl13 = p >> 19;
                unsigned s = p & 0x7FFFFu;
                unsigned j = dl13 >> 8;
                unsigned q = ((dl13 & 255u) << 19) | s;
                int pos = atomicAdd(&lcnt[j], 1);
                if (pos < CAPB) stage[j * CAPB + pos] = q;
                else { int slot = atomicAdd(&bcur[f0 + j], 1); ebufB[slot] = q; }
            }
        }
        __syncthreads();
        if (tid < 32) nn[tid] = (tid < lb) ? min(lcnt[tid], CAPB) : 0;
        __syncthreads();
        if (tid == 0) {
            int r = 0;
            for (int b = 0; b < 32; ++b) { soff[b] = r; r += nn[b]; }
            stot = r;
        }
        __syncthreads();
        if (tid < 32 && nn[tid] > 0) sbase[tid] = atomicAdd(&bcur[f0 + tid], nn[tid]);
        __syncthreads();
        for (int i = tid; i < stot; i += 256) {
            int lo = 0, hi = 31;
            while (lo < hi) { int mid = (lo + hi + 1) >> 1; if (soff[mid] <= i) lo = mid; else hi = mid - 1; }
            int r = i - soff[lo];
            ebufB[sbase[lo] + r] = stage[lo * CAPB + r];
        }
        __syncthreads();
    }
}

// ---- y1 = (x @ W1) * dinv  -> bf16 rows (32 x bf16 = 64B) ----
__global__ __launch_bounds__(256) void k_gemm1(const void* __restrict__ x,
                                               const void* __restrict__ w1,
                                               const float* __restrict__ dinv,
                                               unsigned* __restrict__ y1b,
                                               const int* __restrict__ flag) {
    __shared__ float wlds[IN_DIM * H1];
    const bool isf32 = (*flag != 0);
    for (int i = threadIdx.x; i < IN_DIM * H1; i += 256) wlds[i] = ldf(w1, i, isf32);
    __syncthreads();
    int node = blockIdx.x * 256 + threadIdx.x;
    if (node >= N_NODES) return;
    float acc[H1];
#pragma unroll
    for (int j = 0; j < H1; ++j) acc[j] = 0.f;
    if (isf32) {
        const float4* xr = reinterpret_cast<const float4*>((const float*)x + (size_t)node * IN_DIM);
#pragma unroll
        for (int kk = 0; kk < IN_DIM / 4; ++kk) {
            float4 v = xr[kk];
            float xe[4] = {v.x, v.y, v.z, v.w};
#pragma unroll
            for (int p = 0; p < 4; ++p) {
                const float* wr = &wlds[(kk * 4 + p) * H1];
#pragma unroll
                for (int j = 0; j < H1; ++j) acc[j] += xe[p] * wr[j];
            }
        }
    } else {
        const uint4* xr = reinterpret_cast<const uint4*>((const unsigned short*)x + (size_t)node * IN_DIM);
#pragma unroll
        for (int kk = 0; kk < IN_DIM / 8; ++kk) {
            uint4 xv = xr[kk];
            unsigned uu[4] = {xv.x, xv.y, xv.z, xv.w};
#pragma unroll
            for (int p = 0; p < 4; ++p) {
                float xlo = __uint_as_float(uu[p] << 16);
                float xhi = __uint_as_float(uu[p] & 0xffff0000u);
                const float* w0 = &wlds[(kk * 8 + p * 2) * H1];
                const float* w1r = w0 + H1;
#pragma unroll
                for (int j = 0; j < H1; ++j) acc[j] += xlo * w0[j];
#pragma unroll
                for (int j = 0; j < H1; ++j) acc[j] += xhi * w1r[j];
            }
        }
    }
    float s = dinv[node];
    unsigned o[16];
#pragma unroll
    for (int q = 0; q < 16; ++q) o[q] = pack2bf(acc[2*q] * s, acc[2*q+1] * s);
    uint4* op = reinterpret_cast<uint4*>(y1b + (size_t)node * 16);
#pragma unroll
    for (int r = 0; r < 4; ++r) op[r] = make_uint4(o[4*r], o[4*r+1], o[4*r+2], o[4*r+3]);
}

// ---- push layer 1: LDS aggregation over fine bucket (256 nodes), fused relu+GEMM2 ----
__global__ __launch_bounds__(256) void k_push1(const unsigned* __restrict__ ebufB,
                                               const int* __restrict__ fbase,
                                               const unsigned* __restrict__ y1b,
                                               const float* __restrict__ dinv,
                                               const void* __restrict__ b1,
                                               const void* __restrict__ w2,
                                               unsigned* __restrict__ y2b,
                                               const int* __restrict__ flag) {
    __shared__ float agg[256 * 33];              // [node_local][33] pad: conflict-free
    __shared__ float w2l[H1 * H2];
    __shared__ float b1l[H1];
    const bool isf32 = (*flag != 0);
    int tid = threadIdx.x;
    for (int i = tid; i < 256 * 33; i += 256) agg[i] = 0.f;
    for (int i = tid; i < H1 * H2; i += 256) w2l[i] = ldf(w2, i, isf32);
    if (tid < H1) b1l[tid] = ldf(b1, tid, isf32);
    __syncthreads();

    int b = blockIdx.x;
    int base = fbase[b];
    int n = fbase[b + 1] - base;
    const unsigned short* y1u = reinterpret_cast<const unsigned short*>(y1b);
    int hw = tid >> 5, lane = tid & 31;
    for (int j0 = hw * 32; j0 < n; j0 += 256) {
        unsigned p = (j0 + lane < n) ? ebufB[base + j0 + lane] : 0u;
        int m = min(32, n - j0);
        for (int k = 0; k < m; ++k) {
            unsigned pp = __shfl(p, k, 32);
            unsigned s = pp & 0x7FFFFu;
            unsigned dl = pp >> 19;
            float v = bf2f(y1u[(size_t)s * 32 + lane]);   // 32 lanes = one 64B line
            atomicAdd(&agg[dl * 33 + lane], v);           // ds_add_f32, bank = (dl+lane)&31
        }
    }
    __syncthreads();

    int node = b * 256 + tid;
    if (node >= N_NODES) return;
    float sc = dinv[node];
    const uint4* sp = reinterpret_cast<const uint4*>(y1b + (size_t)node * 16);
    float h[H1];
#pragma unroll
    for (int r = 0; r < 4; ++r) {
        uint4 q = sp[r];
        unsigned uu[4] = {q.x, q.y, q.z, q.w};
#pragma unroll
        for (int w = 0; w < 4; ++w) {
            int k = r * 8 + w * 2;
            float lo = __uint_as_float(uu[w] << 16);
            float hi = __uint_as_float(uu[w] & 0xffff0000u);
            float v0 = sc * (agg[tid * 33 + k] + lo) + b1l[k];
            float v1 = sc * (agg[tid * 33 + k + 1] + hi) + b1l[k + 1];
            h[k] = v0 > 0.f ? v0 : 0.f;
            h[k + 1] = v1 > 0.f ? v1 : 0.f;
        }
    }
    float a2[H2];
#pragma unroll
    for (int j = 0; j < H2; ++j) a2[j] = 0.f;
#pragma unroll
    for (int k = 0; k < H1; ++k) {
        float hk = h[k];
#pragma unroll
        for (int j = 0; j < H2; ++j) a2[j] += hk * w2l[k * H2 + j];
    }
    unsigned o[8];
#pragma unroll
    for (int q = 0; q < 8; ++q) o[q] = pack2bf(a2[2*q] * sc, a2[2*q+1] * sc);
    uint4* op = reinterpret_cast<uint4*>(y2b + (size_t)node * 8);
    op[0] = make_uint4(o[0], o[1], o[2], o[3]);
    op[1] = make_uint4(o[4], o[5], o[6], o[7]);
}

// ---- push layer 2: LDS aggregation, fused relu+FC+log_softmax ----
__global__ __launch_bounds__(256) void k_push2(const unsigned* __restrict__ ebufB,
                                               const int* __restrict__ fbase,
                                               const unsigned* __restrict__ y2b,
                                               const float* __restrict__ dinv,
                                               const void* __restrict__ b2,
                                               const void* __restrict__ wfc,
                                               const void* __restrict__ bfc,
                                               void* __restrict__ out,
                                               const int* __restrict__ flag) {
    __shared__ float agg[256 * 17];              // [node_local][17]
    __shared__ float wl[H2 * 2];
    __shared__ float b2l[H2];
    __shared__ float bfl[2];
    const bool isf32 = (*flag != 0);
    int tid = threadIdx.x;
    for (int i = tid; i < 256 * 17; i += 256) agg[i] = 0.f;
    if (tid < H2 * 2) wl[tid] = ldf(wfc, tid, isf32);
    if (tid < H2) b2l[tid] = ldf(b2, tid, isf32);
    if (tid < 2) bfl[tid] = ldf(bfc, tid, isf32);
    __syncthreads();

    int b = blockIdx.x;
    int base = fbase[b];
    int n = fbase[b + 1] - base;
    const unsigned short* y2u = reinterpret_cast<const unsigned short*>(y2b);
    int hw = tid >> 4, lane = tid & 15;          // 16 groups of 16 lanes
    for (int j0 = hw * 16; j0 < n; j0 += 256) {
        unsigned p = (j0 + lane < n) ? ebufB[base + j0 + lane] : 0u;
        int m = min(16, n - j0);
        for (int k = 0; k < m; ++k) {
            unsigned pp = __shfl(p, k, 16);
            unsigned s = pp & 0x7FFFFu;
            unsigned dl = pp >> 19;
            float v = bf2f(y2u[(size_t)s * 16 + lane]);
            atomicAdd(&agg[dl * 17 + lane], v);
        }
    }
    __syncthreads();

    int node = b * 256 + tid;
    if (node >= N_NODES) return;
    float sc = dinv[node];
    const uint4* sp = reinterpret_cast<const uint4*>(y2b + (size_t)node * 8);
    float l0 = bfl[0], l1 = bfl[1];
#pragma unroll
    for (int r = 0; r < 2; ++r) {
        uint4 q = sp[r];
        unsigned uu[4] = {q.x, q.y, q.z, q.w};
#pragma unroll
        for (int w = 0; w < 4; ++w) {
            int k = r * 8 + w * 2;
            float lo = __uint_as_float(uu[w] << 16);
            float hi = __uint_as_float(uu[w] & 0xffff0000u);
            float v0 = sc * (agg[tid * 17 + k] + lo) + b2l[k];
            float v1 = sc * (agg[tid * 17 + k + 1] + hi) + b2l[k + 1];
            v0 = v0 > 0.f ? v0 : 0.f;
            v1 = v1 > 0.f ? v1 : 0.f;
            l0 += v0 * wl[k * 2] + v1 * wl[(k + 1) * 2];
            l1 += v0 * wl[k * 2 + 1] + v1 * wl[(k + 1) * 2 + 1];
        }
    }
    float mx = fmaxf(l0, l1);
    float lse = mx + logf(__expf(l0 - mx) + __expf(l1 - mx));
    if (isf32) {
        reinterpret_cast<float2*>(out)[node] = make_float2(l0 - lse, l1 - lse);
    } else {
        reinterpret_cast<unsigned*>(out)[node] =
            (unsigned)f2bf(l0 - lse) | ((unsigned)f2bf(l1 - lse) << 16);
    }
}

extern "C" void kernel_launch(void* const* d_in, const int* in_sizes, int n_in,
                              void* d_out, int out_size, void* d_ws, size_t ws_size,
                              hipStream_t stream) {
    const void* x   = d_in[0];
    const int*  ei  = (const int*)d_in[1];
    const void* w1  = d_in[2];
    const void* b1  = d_in[3];
    const void* w2  = d_in[4];
    const void* b2  = d_in[5];
    const void* wfc = d_in[6];
    const void* bfc = d_in[7];
    const int* src = ei;
    const int* dst = ei + N_EDGES;

    // workspace (4B units), total ~116 MB:
    // flag@0 | dinv@64 | cnt@500288(500224) | fhist@1000512(2048) | fbase@1002560(1955)
    // acur@1004608(64) | bcur@1004672(2048) | ebufA@1006720(8M) | ebufB@9006720(8M)
    // y1b@17006720(8003584 u32) | y2b@25010304(4001792 u32)
    float*    ws    = (float*)d_ws;
    int*      flag  = (int*)ws;
    float*    dinv  = ws + 64;
    int*      cnt   = (int*)(ws + 500288);
    int*      fhist = (int*)(ws + 1000512);
    int*      fbase = (int*)(ws + 1002560);
    int*      acur  = (int*)(ws + 1004608);
    int*      bcur  = (int*)(ws + 1004672);
    unsigned* ebufA = (unsigned*)(ws + 1006720);
    unsigned* ebufB = (unsigned*)(ws + 9006720);
    unsigned* y1b   = (unsigned*)(ws + 17006720);
    unsigned* y2b   = (unsigned*)(ws + 25010304);

    k_sniff<<<1, 64, 0, stream>>>((const unsigned int*)x, flag);
    hipMemsetAsync(cnt, 0, (size_t)500224 * sizeof(int), stream);
    k_hist<<<4096, 256, 0, stream>>>(dst, cnt);
    k_fhist<<<NFINE, 256, 0, stream>>>(cnt, fhist);
    k_scanf<<<1, 256, 0, stream>>>(fhist, fbase, bcur, acur);
    k_dinv<<<NB_NODES, 256, 0, stream>>>(cnt, dinv);
    k_gemm1<<<NB_NODES, 256, 0, stream>>>(x, w1, dinv, y1b, flag);
    k_scatA<<<977, 256, 0, stream>>>(src, dst, acur, ebufA);
    k_scatB<<<NCOARSE * 8, 256, 0, stream>>>(ebufA, fbase, bcur, ebufB);
    k_push1<<<NFINE, 256, 0, stream>>>(ebufB, fbase, y1b, dinv, b1, w2, y2b, flag);
    k_push2<<<NFINE, 256, 0, stream>>>(ebufB, fbase, y2b, dinv, b2, wfc, bfc, d_out, flag);
}

// Round 5
// 2987.766 us; speedup vs baseline: 1.0327x; 1.0327x over previous
//
#include <hip/hip_runtime.h>

#define N_NODES 500000
#define N_EDGES 8000000
#define IN_DIM 128
#define H1 32
#define H2 16
#define NB_NODES 1954        // ceil(500000/256) = fine buckets of 256 nodes
#define NFINE 1954
#define NCOARSE 62           // node>>13 -> 0..61
#define CAPA 200             // stage capacity, coarse multisplit (chunk 8192, mean 132)
#define CAPB 340             // stage capacity, fine multisplit (chunk 8192/32 buckets, mean 256)

static __device__ __forceinline__ float bf2f(unsigned short u) {
    return __uint_as_float(((unsigned int)u) << 16);
}
static __device__ __forceinline__ unsigned short f2bf(float f) {
    unsigned int u = __float_as_uint(f);
    unsigned int r = (u + 0x7fffu + ((u >> 16) & 1u)) >> 16;
    return (unsigned short)r;
}
static __device__ __forceinline__ unsigned pack2bf(float a, float b) {
    return (unsigned)f2bf(a) | ((unsigned)f2bf(b) << 16);
}
static __device__ __forceinline__ float ldf(const void* p, int i, bool isf32) {
    return isf32 ? ((const float*)p)[i] : bf2f(((const unsigned short*)p)[i]);
}

// ---- dtype sniffer: low 16 bits of fp32 mantissas decode to wild bf16s ----
__global__ __launch_bounds__(64) void k_sniff(const unsigned int* __restrict__ x,
                                              int* __restrict__ flag) {
    int bad = 0;
    for (int i = threadIdx.x; i < 1024; i += 64) {
        float v = __uint_as_float((x[i] & 0xffffu) << 16);
        if (!(fabsf(v) < 1e6f)) bad = 1;
    }
    unsigned long long m = __ballot(bad);
    if (threadIdx.x == 0) *flag = (m != 0ull) ? 1 : 0;
}

// ---- node in-degree histogram ----
__global__ __launch_bounds__(256) void k_hist(const int* __restrict__ dst,
                                              int* __restrict__ cnt) {
    int i = blockIdx.x * blockDim.x + threadIdx.x;
    int stride = gridDim.x * blockDim.x;
    for (int e = i; e < N_EDGES; e += stride) {
        unsigned d = (unsigned)dst[e];
        if (d < N_NODES) atomicAdd(&cnt[d], 1);
    }
}

// ---- fine-bucket histogram: fhist[b] = sum cnt[b*256 .. b*256+255] ----
__global__ __launch_bounds__(256) void k_fhist(const int* __restrict__ cnt,
                                               int* __restrict__ fhist) {
    __shared__ int red[256];
    int tid = threadIdx.x;
    red[tid] = cnt[blockIdx.x * 256 + tid];   // cnt sized/zeroed to 500224
    __syncthreads();
    for (int o = 128; o > 0; o >>= 1) {
        if (tid < o) red[tid] += red[tid + o];
        __syncthreads();
    }
    if (tid == 0) fhist[blockIdx.x] = red[0];
}

// ---- single-block exclusive scan over 1954 fine buckets; emits cursors ----
__global__ __launch_bounds__(256) void k_scanf(const int* __restrict__ fhist,
                                               int* __restrict__ fbase,
                                               int* __restrict__ bcur,
                                               int* __restrict__ acur) {
    __shared__ int tmp[256];
    __shared__ int s_run;
    int tid = threadIdx.x;
    if (tid == 0) s_run = 0;
    __syncthreads();
    for (int base = 0; base < 2048; base += 256) {
        int i = base + tid;
        int v = (i < NFINE) ? fhist[i] : 0;
        int val = v;
        tmp[tid] = val;
        __syncthreads();
        for (int o = 1; o < 256; o <<= 1) {
            int t = (tid >= o) ? tmp[tid - o] : 0;
            __syncthreads();
            val += t;
            tmp[tid] = val;
            __syncthreads();
        }
        int run = s_run;
        if (i < NFINE) {
            int ex = run + val - v;
            fbase[i] = ex;
            bcur[i] = ex;
            if ((i & 31) == 0) acur[i >> 5] = ex;  // coarse cursor = fine boundary
        }
        __syncthreads();
        if (tid == 255) s_run = run + val;
        __syncthreads();
    }
    if (tid == 0) fbase[NFINE] = s_run;
}

// ---- dinv = rsqrt(deg+1) ----
__global__ __launch_bounds__(256) void k_dinv(const int* __restrict__ cnt,
                                              float* __restrict__ dinv) {
    int i = blockIdx.x * 256 + threadIdx.x;
    if (i < N_NODES) dinv[i] = rsqrtf((float)cnt[i] + 1.0f);
}

// ---- multisplit level A: raw edges -> 62 coarse buckets, 4B packed entries ----
// entry = (dst_local13 << 19) | src
__global__ __launch_bounds__(256) void k_scatA(const int* __restrict__ src,
                                               const int* __restrict__ dst,
                                               int* __restrict__ acur,
                                               unsigned* __restrict__ ebufA) {
    __shared__ unsigned stage[NCOARSE * CAPA];   // 49.6 KB
    __shared__ int lcnt[NCOARSE], nn[NCOARSE], soff[NCOARSE], sbase[NCOARSE];
    __shared__ int stot;
    int tid = threadIdx.x;
    int cb = blockIdx.x * 8192;                  // 977 blocks, one chunk each
    if (tid < NCOARSE) lcnt[tid] = 0;
    __syncthreads();
    for (int i = 0; i < 32; ++i) {
        int e = cb + (i << 8) + tid;
        if (e < N_EDGES) {
            unsigned d = (unsigned)dst[e], s = (unsigned)src[e];
            if (d < N_NODES) {                   // match k_hist's guard exactly
                unsigned b = d >> 13;
                unsigned p = ((d & 8191u) << 19) | s;
                int pos = atomicAdd(&lcnt[b], 1);
                if (pos < CAPA) stage[b * CAPA + pos] = p;
                else { int slot = atomicAdd(&acur[b], 1); ebufA[slot] = p; }
            }
        }
    }
    __syncthreads();
    if (tid < NCOARSE) nn[tid] = min(lcnt[tid], CAPA);
    __syncthreads();
    if (tid == 0) {
        int r = 0;
        for (int b = 0; b < NCOARSE; ++b) { soff[b] = r; r += nn[b]; }
        stot = r;
    }
    __syncthreads();
    if (tid < NCOARSE && nn[tid] > 0) sbase[tid] = atomicAdd(&acur[tid], nn[tid]);
    __syncthreads();
    for (int i = tid; i < stot; i += 256) {      // coalesced full-line flush
        int lo = 0, hi = NCOARSE - 1;
        while (lo < hi) { int mid = (lo + hi + 1) >> 1; if (soff[mid] <= i) lo = mid; else hi = mid - 1; }
        int r = i - soff[lo];
        ebufA[sbase[lo] + r] = stage[lo * CAPA + r];
    }
}

// ---- multisplit level B: coarse bucket -> 32 fine buckets (256 nodes each) ----
// entry out = (dst_local8 << 19) | src
__global__ __launch_bounds__(256) void k_scatB(const unsigned* __restrict__ ebufA,
                                               const int* __restrict__ fbase,
                                               int* __restrict__ bcur,
                                               unsigned* __restrict__ ebufB) {
    __shared__ unsigned stage[32 * CAPB];        // 43.5 KB
    __shared__ int lcnt[32], nn[32], soff[32], sbase[32];
    __shared__ int stot;
    int tid = threadIdx.x;
    int a = blockIdx.x >> 3, sub = blockIdx.x & 7;
    int f0 = a * 32;
    int lb = min(32, NFINE - f0);
    int abase = fbase[f0];
    int aend = fbase[min(f0 + 32, NFINE)];
    for (int cb = abase + sub * 8192; cb < aend; cb += 8 * 8192) {
        if (tid < 32) lcnt[tid] = 0;
        __syncthreads();
        for (int i = 0; i < 32; ++i) {
            int e = cb + (i << 8) + tid;
            if (e < aend) {
                unsigned p = ebufA[e];
                unsigned dl13 = p >> 19;
                unsigned s = p & 0x7FFFFu;
                unsigned j = dl13 >> 8;
                unsigned q = ((dl13 & 255u) << 19) | s;
                int pos = atomicAdd(&lcnt[j], 1);
                if (pos < CAPB) stage[j * CAPB + pos] = q;
                else { int slot = atomicAdd(&bcur[f0 + j], 1); ebufB[slot] = q; }
            }
        }
        __syncthreads();
        if (tid < 32) nn[tid] = (tid < lb) ? min(lcnt[tid], CAPB) : 0;
        __syncthreads();
        if (tid == 0) {
            int r = 0;
            for (int b = 0; b < 32; ++b) { soff[b] = r; r += nn[b]; }
            stot = r;
        }
        __syncthreads();
        if (tid < 32 && nn[tid] > 0) sbase[tid] = atomicAdd(&bcur[f0 + tid], nn[tid]);
        __syncthreads();
        for (int i = tid; i < stot; i += 256) {
            int lo = 0, hi = 31;
            while (lo < hi) { int mid = (lo + hi + 1) >> 1; if (soff[mid] <= i) lo = mid; else hi = mid - 1; }
            int r = i - soff[lo];
            ebufB[sbase[lo] + r] = stage[lo * CAPB + r];
        }
        __syncthreads();
    }
}

// ---- y1 = (x @ W1) * dinv  -> bf16 rows (32 x bf16 = 64B) ----
__global__ __launch_bounds__(256) void k_gemm1(const void* __restrict__ x,
                                               const void* __restrict__ w1,
                                               const float* __restrict__ dinv,
                                               unsigned* __restrict__ y1b,
                                               const int* __restrict__ flag) {
    __shared__ float wlds[IN_DIM * H1];
    const bool isf32 = (*flag != 0);
    for (int i = threadIdx.x; i < IN_DIM * H1; i += 256) wlds[i] = ldf(w1, i, isf32);
    __syncthreads();
    int node = blockIdx.x * 256 + threadIdx.x;
    if (node >= N_NODES) return;
    float acc[H1];
#pragma unroll
    for (int j = 0; j < H1; ++j) acc[j] = 0.f;
    if (isf32) {
        const float4* xr = reinterpret_cast<const float4*>((const float*)x + (size_t)node * IN_DIM);
#pragma unroll
        for (int kk = 0; kk < IN_DIM / 4; ++kk) {
            float4 v = xr[kk];
            float xe[4] = {v.x, v.y, v.z, v.w};
#pragma unroll
            for (int p = 0; p < 4; ++p) {
                const float* wr = &wlds[(kk * 4 + p) * H1];
#pragma unroll
                for (int j = 0; j < H1; ++j) acc[j] += xe[p] * wr[j];
            }
        }
    } else {
        const uint4* xr = reinterpret_cast<const uint4*>((const unsigned short*)x + (size_t)node * IN_DIM);
#pragma unroll
        for (int kk = 0; kk < IN_DIM / 8; ++kk) {
            uint4 xv = xr[kk];
            unsigned uu[4] = {xv.x, xv.y, xv.z, xv.w};
#pragma unroll
            for (int p = 0; p < 4; ++p) {
                float xlo = __uint_as_float(uu[p] << 16);
                float xhi = __uint_as_float(uu[p] & 0xffff0000u);
                const float* w0 = &wlds[(kk * 8 + p * 2) * H1];
                const float* w1r = w0 + H1;
#pragma unroll
                for (int j = 0; j < H1; ++j) acc[j] += xlo * w0[j];
#pragma unroll
                for (int j = 0; j < H1; ++j) acc[j] += xhi * w1r[j];
            }
        }
    }
    float s = dinv[node];
    unsigned o[16];
#pragma unroll
    for (int q = 0; q < 16; ++q) o[q] = pack2bf(acc[2*q] * s, acc[2*q+1] * s);
    uint4* op = reinterpret_cast<uint4*>(y1b + (size_t)node * 16);
#pragma unroll
    for (int r = 0; r < 4; ++r) op[r] = make_uint4(o[4*r], o[4*r+1], o[4*r+2], o[4*r+3]);
}

// ---- push layer 1: edge-parallel gather + LDS atomic agg, fused relu+GEMM2 ----
// Each thread owns one edge per step: coalesced entry load, 4 independent
// uint4 gathers of its row (high MLP), 32 ds_add_f32 into agg[dl].
__global__ __launch_bounds__(256) void k_push1(const unsigned* __restrict__ ebufB,
                                               const int* __restrict__ fbase,
                                               const unsigned* __restrict__ y1b,
                                               const float* __restrict__ dinv,
                                               const void* __restrict__ b1,
                                               const void* __restrict__ w2,
                                               unsigned* __restrict__ y2b,
                                               const int* __restrict__ flag) {
    __shared__ float agg[256 * 33];              // [node_local][33] pad: conflict-free
    __shared__ float w2l[H1 * H2];
    __shared__ float b1l[H1];
    const bool isf32 = (*flag != 0);
    int tid = threadIdx.x;
    for (int i = tid; i < 256 * 33; i += 256) agg[i] = 0.f;
    for (int i = tid; i < H1 * H2; i += 256) w2l[i] = ldf(w2, i, isf32);
    if (tid < H1) b1l[tid] = ldf(b1, tid, isf32);
    __syncthreads();

    int b = blockIdx.x;
    int base = fbase[b];
    int n = fbase[b + 1] - base;
    for (int j0 = 0; j0 < n; j0 += 256) {
        int e = j0 + tid;
        if (e < n) {
            unsigned p = ebufB[base + e];
            unsigned s = p & 0x7FFFFu;
            unsigned dl = p >> 19;
            const uint4* rp = reinterpret_cast<const uint4*>(y1b + (size_t)s * 16);
            uint4 q0 = rp[0], q1 = rp[1], q2 = rp[2], q3 = rp[3];
            float* arow = &agg[dl * 33];
            unsigned uu[16] = {q0.x, q0.y, q0.z, q0.w, q1.x, q1.y, q1.z, q1.w,
                               q2.x, q2.y, q2.z, q2.w, q3.x, q3.y, q3.z, q3.w};
#pragma unroll
            for (int w = 0; w < 16; ++w) {
                atomicAdd(&arow[2*w],     __uint_as_float(uu[w] << 16));
                atomicAdd(&arow[2*w + 1], __uint_as_float(uu[w] & 0xffff0000u));
            }
        }
    }
    __syncthreads();

    int node = b * 256 + tid;
    if (node >= N_NODES) return;
    float sc = dinv[node];
    const uint4* sp = reinterpret_cast<const uint4*>(y1b + (size_t)node * 16);
    float h[H1];
#pragma unroll
    for (int r = 0; r < 4; ++r) {
        uint4 q = sp[r];
        unsigned uu[4] = {q.x, q.y, q.z, q.w};
#pragma unroll
        for (int w = 0; w < 4; ++w) {
            int k = r * 8 + w * 2;
            float lo = __uint_as_float(uu[w] << 16);
            float hi = __uint_as_float(uu[w] & 0xffff0000u);
            float v0 = sc * (agg[tid * 33 + k] + lo) + b1l[k];
            float v1 = sc * (agg[tid * 33 + k + 1] + hi) + b1l[k + 1];
            h[k] = v0 > 0.f ? v0 : 0.f;
            h[k + 1] = v1 > 0.f ? v1 : 0.f;
        }
    }
    float a2[H2];
#pragma unroll
    for (int j = 0; j < H2; ++j) a2[j] = 0.f;
#pragma unroll
    for (int k = 0; k < H1; ++k) {
        float hk = h[k];
#pragma unroll
        for (int j = 0; j < H2; ++j) a2[j] += hk * w2l[k * H2 + j];
    }
    unsigned o[8];
#pragma unroll
    for (int q = 0; q < 8; ++q) o[q] = pack2bf(a2[2*q] * sc, a2[2*q+1] * sc);
    uint4* op = reinterpret_cast<uint4*>(y2b + (size_t)node * 8);
    op[0] = make_uint4(o[0], o[1], o[2], o[3]);
    op[1] = make_uint4(o[4], o[5], o[6], o[7]);
}

// ---- push layer 2: edge-parallel gather + LDS agg, fused relu+FC+log_softmax ----
__global__ __launch_bounds__(256) void k_push2(const unsigned* __restrict__ ebufB,
                                               const int* __restrict__ fbase,
                                               const unsigned* __restrict__ y2b,
                                               const float* __restrict__ dinv,
                                               const void* __restrict__ b2,
                                               const void* __restrict__ wfc,
                                               const void* __restrict__ bfc,
                                               void* __restrict__ out,
                                               const int* __restrict__ flag) {
    __shared__ float agg[256 * 17];              // [node_local][17]
    __shared__ float wl[H2 * 2];
    __shared__ float b2l[H2];
    __shared__ float bfl[2];
    const bool isf32 = (*flag != 0);
    int tid = threadIdx.x;
    for (int i = tid; i < 256 * 17; i += 256) agg[i] = 0.f;
    if (tid < H2 * 2) wl[tid] = ldf(wfc, tid, isf32);
    if (tid < H2) b2l[tid] = ldf(b2, tid, isf32);
    if (tid < 2) bfl[tid] = ldf(bfc, tid, isf32);
    __syncthreads();

    int b = blockIdx.x;
    int base = fbase[b];
    int n = fbase[b + 1] - base;
    for (int j0 = 0; j0 < n; j0 += 256) {
        int e = j0 + tid;
        if (e < n) {
            unsigned p = ebufB[base + e];
            unsigned s = p & 0x7FFFFu;
            unsigned dl = p >> 19;
            const uint4* rp = reinterpret_cast<const uint4*>(y2b + (size_t)s * 8);
            uint4 q0 = rp[0], q1 = rp[1];
            float* arow = &agg[dl * 17];
            unsigned uu[8] = {q0.x, q0.y, q0.z, q0.w, q1.x, q1.y, q1.z, q1.w};
#pragma unroll
            for (int w = 0; w < 8; ++w) {
                atomicAdd(&arow[2*w],     __uint_as_float(uu[w] << 16));
                atomicAdd(&arow[2*w + 1], __uint_as_float(uu[w] & 0xffff0000u));
            }
        }
    }
    __syncthreads();

    int node = b * 256 + tid;
    if (node >= N_NODES) return;
    float sc = dinv[node];
    const uint4* sp = reinterpret_cast<const uint4*>(y2b + (size_t)node * 8);
    float l0 = bfl[0], l1 = bfl[1];
#pragma unroll
    for (int r = 0; r < 2; ++r) {
        uint4 q = sp[r];
        unsigned uu[4] = {q.x, q.y, q.z, q.w};
#pragma unroll
        for (int w = 0; w < 4; ++w) {
            int k = r * 8 + w * 2;
            float lo = __uint_as_float(uu[w] << 16);
            float hi = __uint_as_float(uu[w] & 0xffff0000u);
            float v0 = sc * (agg[tid * 17 + k] + lo) + b2l[k];
            float v1 = sc * (agg[tid * 17 + k + 1] + hi) + b2l[k + 1];
            v0 = v0 > 0.f ? v0 : 0.f;
            v1 = v1 > 0.f ? v1 : 0.f;
            l0 += v0 * wl[k * 2] + v1 * wl[(k + 1) * 2];
            l1 += v0 * wl[k * 2 + 1] + v1 * wl[(k + 1) * 2 + 1];
        }
    }
    float mx = fmaxf(l0, l1);
    float lse = mx + logf(__expf(l0 - mx) + __expf(l1 - mx));
    if (isf32) {
        reinterpret_cast<float2*>(out)[node] = make_float2(l0 - lse, l1 - lse);
    } else {
        reinterpret_cast<unsigned*>(out)[node] =
            (unsigned)f2bf(l0 - lse) | ((unsigned)f2bf(l1 - lse) << 16);
    }
}

extern "C" void kernel_launch(void* const* d_in, const int* in_sizes, int n_in,
                              void* d_out, int out_size, void* d_ws, size_t ws_size,
                              hipStream_t stream) {
    const void* x   = d_in[0];
    const int*  ei  = (const int*)d_in[1];
    const void* w1  = d_in[2];
    const void* b1  = d_in[3];
    const void* w2  = d_in[4];
    const void* b2  = d_in[5];
    const void* wfc = d_in[6];
    const void* bfc = d_in[7];
    const int* src = ei;
    const int* dst = ei + N_EDGES;

    // workspace (4B units), total ~116 MB:
    // flag@0 | dinv@64 | cnt@500288(500224) | fhist@1000512(2048) | fbase@1002560(1955)
    // acur@1004608(64) | bcur@1004672(2048) | ebufA@1006720(8M) | ebufB@9006720(8M)
    // y1b@17006720(8003584 u32) | y2b@25010304(4001792 u32)
    float*    ws    = (float*)d_ws;
    int*      flag  = (int*)ws;
    float*    dinv  = ws + 64;
    int*      cnt   = (int*)(ws + 500288);
    int*      fhist = (int*)(ws + 1000512);
    int*      fbase = (int*)(ws + 1002560);
    int*      acur  = (int*)(ws + 1004608);
    int*      bcur  = (int*)(ws + 1004672);
    unsigned* ebufA = (unsigned*)(ws + 1006720);
    unsigned* ebufB = (unsigned*)(ws + 9006720);
    unsigned* y1b   = (unsigned*)(ws + 17006720);
    unsigned* y2b   = (unsigned*)(ws + 25010304);

    k_sniff<<<1, 64, 0, stream>>>((const unsigned int*)x, flag);
    hipMemsetAsync(cnt, 0, (size_t)500224 * sizeof(int), stream);
    k_hist<<<4096, 256, 0, stream>>>(dst, cnt);
    k_fhist<<<NFINE, 256, 0, stream>>>(cnt, fhist);
    k_scanf<<<1, 256, 0, stream>>>(fhist, fbase, bcur, acur);
    k_dinv<<<NB_NODES, 256, 0, stream>>>(cnt, dinv);
    k_gemm1<<<NB_NODES, 256, 0, stream>>>(x, w1, dinv, y1b, flag);
    k_scatA<<<977, 256, 0, stream>>>(src, dst, acur, ebufA);
    k_scatB<<<NCOARSE * 8, 256, 0, stream>>>(ebufA, fbase, bcur, ebufB);
    k_push1<<<NFINE, 256, 0, stream>>>(ebufB, fbase, y1b, dinv, b1, w2, y2b, flag);
    k_push2<<<NFINE, 256, 0, stream>>>(ebufB, fbase, y2b, dinv, b2, wfc, bfc, d_out, flag);
}

// Round 6
// 1023.476 us; speedup vs baseline: 3.0146x; 2.9192x over previous
//
#include <hip/hip_runtime.h>

#define N_NODES 500000
#define N_EDGES 8000000
#define IN_DIM 128
#define H1 32
#define H2 16
#define NFINE 1954           // fine buckets of 256 nodes (1954*256 = 500224)
#define NCOARSE 62           // node>>13 -> 0..61
#define CAPA 200             // stage capacity, coarse multisplit
#define CAPB 340             // stage capacity, fine multisplit

static __device__ __forceinline__ float bf2f(unsigned short u) {
    return __uint_as_float(((unsigned int)u) << 16);
}
static __device__ __forceinline__ unsigned short f2bf(float f) {
    unsigned int u = __float_as_uint(f);
    unsigned int r = (u + 0x7fffu + ((u >> 16) & 1u)) >> 16;
    return (unsigned short)r;
}
static __device__ __forceinline__ unsigned pack2bf(float a, float b) {
    return (unsigned)f2bf(a) | ((unsigned)f2bf(b) << 16);
}
static __device__ __forceinline__ float ldf(const void* p, int i, bool isf32) {
    return isf32 ? ((const float*)p)[i] : bf2f(((const unsigned short*)p)[i]);
}

// ---- dtype sniffer ----
__global__ __launch_bounds__(64) void k_sniff(const unsigned int* __restrict__ x,
                                              int* __restrict__ flag) {
    int bad = 0;
    for (int i = threadIdx.x; i < 1024; i += 64) {
        float v = __uint_as_float((x[i] & 0xffffu) << 16);
        if (!(fabsf(v) < 1e6f)) bad = 1;
    }
    unsigned long long m = __ballot(bad);
    if (threadIdx.x == 0) *flag = (m != 0ull) ? 1 : 0;
}

// ---- fine-bucket histogram via LDS (replaces 8M-global-atomic k_hist) ----
__global__ __launch_bounds__(256) void k_bhist(const int* __restrict__ dst,
                                               int* __restrict__ fhist) {
    __shared__ int h[2048];
    int tid = threadIdx.x;
    for (int i = tid; i < 2048; i += 256) h[i] = 0;
    __syncthreads();
    int i = blockIdx.x * 256 + tid;
    int stride = gridDim.x * 256;
    for (int e = i; e < N_EDGES; e += stride) {
        unsigned d = (unsigned)dst[e];
        if (d < N_NODES) atomicAdd(&h[d >> 8], 1);
    }
    __syncthreads();
    for (int i2 = tid; i2 < 2048; i2 += 256)
        if (h[i2]) atomicAdd(&fhist[i2], h[i2]);
}

// ---- single-block exclusive scan over fine buckets; emits cursors ----
__global__ __launch_bounds__(256) void k_scanf(const int* __restrict__ fhist,
                                               int* __restrict__ fbase,
                                               int* __restrict__ bcur,
                                               int* __restrict__ acur) {
    __shared__ int tmp[256];
    __shared__ int s_run;
    int tid = threadIdx.x;
    if (tid == 0) s_run = 0;
    __syncthreads();
    for (int base = 0; base < 2048; base += 256) {
        int i = base + tid;
        int v = (i < NFINE) ? fhist[i] : 0;
        int val = v;
        tmp[tid] = val;
        __syncthreads();
        for (int o = 1; o < 256; o <<= 1) {
            int t = (tid >= o) ? tmp[tid - o] : 0;
            __syncthreads();
            val += t;
            tmp[tid] = val;
            __syncthreads();
        }
        int run = s_run;
        if (i < NFINE) {
            int ex = run + val - v;
            fbase[i] = ex;
            bcur[i] = ex;
            if ((i & 31) == 0) acur[i >> 5] = ex;
        }
        __syncthreads();
        if (tid == 255) s_run = run + val;
        __syncthreads();
    }
    if (tid == 0) fbase[NFINE] = s_run;
}

// ---- multisplit level A: raw edges -> 62 coarse buckets ----
// entry = (dst_local13 << 19) | src
__global__ __launch_bounds__(256) void k_scatA(const int* __restrict__ src,
                                               const int* __restrict__ dst,
                                               int* __restrict__ acur,
                                               unsigned* __restrict__ ebufA) {
    __shared__ unsigned stage[NCOARSE * CAPA];
    __shared__ int lcnt[NCOARSE], nn[NCOARSE], soff[NCOARSE], sbase[NCOARSE];
    __shared__ int stot;
    int tid = threadIdx.x;
    int cb = blockIdx.x * 8192;
    if (tid < NCOARSE) lcnt[tid] = 0;
    __syncthreads();
    for (int i = 0; i < 32; ++i) {
        int e = cb + (i << 8) + tid;
        if (e < N_EDGES) {
            unsigned d = (unsigned)dst[e], s = (unsigned)src[e];
            if (d < N_NODES) {
                unsigned b = d >> 13;
                unsigned p = ((d & 8191u) << 19) | s;
                int pos = atomicAdd(&lcnt[b], 1);
                if (pos < CAPA) stage[b * CAPA + pos] = p;
                else { int slot = atomicAdd(&acur[b], 1); ebufA[slot] = p; }
            }
        }
    }
    __syncthreads();
    if (tid < NCOARSE) nn[tid] = min(lcnt[tid], CAPA);
    __syncthreads();
    if (tid == 0) {
        int r = 0;
        for (int b = 0; b < NCOARSE; ++b) { soff[b] = r; r += nn[b]; }
        stot = r;
    }
    __syncthreads();
    if (tid < NCOARSE && nn[tid] > 0) sbase[tid] = atomicAdd(&acur[tid], nn[tid]);
    __syncthreads();
    for (int i = tid; i < stot; i += 256) {
        int lo = 0, hi = NCOARSE - 1;
        while (lo < hi) { int mid = (lo + hi + 1) >> 1; if (soff[mid] <= i) lo = mid; else hi = mid - 1; }
        int r = i - soff[lo];
        ebufA[sbase[lo] + r] = stage[lo * CAPA + r];
    }
}

// ---- multisplit level B: coarse -> 32 fine buckets; entry=(dst_local8<<19)|src ----
__global__ __launch_bounds__(256) void k_scatB(const unsigned* __restrict__ ebufA,
                                               const int* __restrict__ fbase,
                                               int* __restrict__ bcur,
                                               unsigned* __restrict__ ebufB) {
    __shared__ unsigned stage[32 * CAPB];
    __shared__ int lcnt[32], nn[32], soff[32], sbase[32];
    __shared__ int stot;
    int tid = threadIdx.x;
    int a = blockIdx.x >> 3, sub = blockIdx.x & 7;
    int f0 = a * 32;
    int lb = min(32, NFINE - f0);
    int abase = fbase[f0];
    int aend = fbase[min(f0 + 32, NFINE)];
    for (int cb = abase + sub * 8192; cb < aend; cb += 8 * 8192) {
        if (tid < 32) lcnt[tid] = 0;
        __syncthreads();
        for (int i = 0; i < 32; ++i) {
            int e = cb + (i << 8) + tid;
            if (e < aend) {
                unsigned p = ebufA[e];
                unsigned dl13 = p >> 19;
                unsigned s = p & 0x7FFFFu;
                unsigned j = dl13 >> 8;
                unsigned q = ((dl13 & 255u) << 19) | s;
                int pos = atomicAdd(&lcnt[j], 1);
                if (pos < CAPB) stage[j * CAPB + pos] = q;
                else { int slot = atomicAdd(&bcur[f0 + j], 1); ebufB[slot] = q; }
            }
        }
        __syncthreads();
        if (tid < 32) nn[tid] = (tid < lb) ? min(lcnt[tid], CAPB) : 0;
        __syncthreads();
        if (tid == 0) {
            int r = 0;
            for (int b = 0; b < 32; ++b) { soff[b] = r; r += nn[b]; }
            stot = r;
        }
        __syncthreads();
        if (tid < 32 && nn[tid] > 0) sbase[tid] = atomicAdd(&bcur[f0 + tid], nn[tid]);
        __syncthreads();
        for (int i = tid; i < stot; i += 256) {
            int lo = 0, hi = 31;
            while (lo < hi) { int mid = (lo + hi + 1) >> 1; if (soff[mid] <= i) lo = mid; else hi = mid - 1; }
            int r = i - soff[lo];
            ebufB[sbase[lo] + r] = stage[lo * CAPB + r];
        }
        __syncthreads();
    }
}

// ---- CSR build per fine bucket: counts+scan in LDS; csr stores hit a 16KB
//      L2-resident window (full-line writeback, unlike global-random fill).
//      Also emits per-node off[] and dinv[]. ----
__global__ __launch_bounds__(256) void k_csr(const unsigned* __restrict__ ebufB,
                                             const int* __restrict__ fbase,
                                             int* __restrict__ csr,
                                             int* __restrict__ off,
                                             float* __restrict__ dinv) {
    __shared__ int cnt[256], ctmp[256], ccur[256];
    int tid = threadIdx.x;
    int b = blockIdx.x;
    int base = fbase[b];
    int n = fbase[b + 1] - base;
    cnt[tid] = 0;
    __syncthreads();
    for (int i = tid; i < n; i += 256) {
        unsigned dl = ebufB[base + i] >> 19;
        atomicAdd(&cnt[dl], 1);
    }
    __syncthreads();
    int v = cnt[tid];
    int val = v;
    ctmp[tid] = val;
    __syncthreads();
    for (int o = 1; o < 256; o <<= 1) {
        int t = (tid >= o) ? ctmp[tid - o] : 0;
        __syncthreads();
        val += t;
        ctmp[tid] = val;
        __syncthreads();
    }
    int excl = val - v;
    off[b * 256 + tid] = base + excl;
    ccur[tid] = excl;
    dinv[b * 256 + tid] = rsqrtf((float)v + 1.0f);
    __syncthreads();
    for (int i = tid; i < n; i += 256) {
        unsigned p = ebufB[base + i];
        unsigned dl = p >> 19;
        int slot = atomicAdd(&ccur[dl], 1);
        csr[base + slot] = (int)(p & 0x7FFFFu);
    }
}

// ---- y1 = (x @ W1) * dinv  -> bf16 rows (32 x bf16 = 64B) ----
__global__ __launch_bounds__(256) void k_gemm1(const void* __restrict__ x,
                                               const void* __restrict__ w1,
                                               const float* __restrict__ dinv,
                                               unsigned* __restrict__ y1b,
                                               const int* __restrict__ flag) {
    __shared__ float wlds[IN_DIM * H1];
    const bool isf32 = (*flag != 0);
    for (int i = threadIdx.x; i < IN_DIM * H1; i += 256) wlds[i] = ldf(w1, i, isf32);
    __syncthreads();
    int node = blockIdx.x * 256 + threadIdx.x;
    if (node >= N_NODES) return;
    float acc[H1];
#pragma unroll
    for (int j = 0; j < H1; ++j) acc[j] = 0.f;
    if (isf32) {
        const float4* xr = reinterpret_cast<const float4*>((const float*)x + (size_t)node * IN_DIM);
#pragma unroll
        for (int kk = 0; kk < IN_DIM / 4; ++kk) {
            float4 v = xr[kk];
            float xe[4] = {v.x, v.y, v.z, v.w};
#pragma unroll
            for (int p = 0; p < 4; ++p) {
                const float* wr = &wlds[(kk * 4 + p) * H1];
#pragma unroll
                for (int j = 0; j < H1; ++j) acc[j] += xe[p] * wr[j];
            }
        }
    } else {
        const uint4* xr = reinterpret_cast<const uint4*>((const unsigned short*)x + (size_t)node * IN_DIM);
#pragma unroll
        for (int kk = 0; kk < IN_DIM / 8; ++kk) {
            uint4 xv = xr[kk];
            unsigned uu[4] = {xv.x, xv.y, xv.z, xv.w};
#pragma unroll
            for (int p = 0; p < 4; ++p) {
                float xlo = __uint_as_float(uu[p] << 16);
                float xhi = __uint_as_float(uu[p] & 0xffff0000u);
                const float* w0 = &wlds[(kk * 8 + p * 2) * H1];
                const float* w1r = w0 + H1;
#pragma unroll
                for (int j = 0; j < H1; ++j) acc[j] += xlo * w0[j];
#pragma unroll
                for (int j = 0; j < H1; ++j) acc[j] += xhi * w1r[j];
            }
        }
    }
    float s = dinv[node];
    unsigned o[16];
#pragma unroll
    for (int q = 0; q < 16; ++q) o[q] = pack2bf(acc[2*q] * s, acc[2*q+1] * s);
    uint4* op = reinterpret_cast<uint4*>(y1b + (size_t)node * 16);
#pragma unroll
    for (int r = 0; r < 4; ++r) op[r] = make_uint4(o[4*r], o[4*r+1], o[4*r+2], o[4*r+3]);
}

// ---- pull layer 1: 16 lanes/node, ILP-4 row gathers, fused relu+GEMM2 ----
__global__ __launch_bounds__(256) void k_pull1(const int* __restrict__ off,
                                               const int* __restrict__ csr,
                                               const unsigned* __restrict__ y1b,
                                               const float* __restrict__ dinv,
                                               const void* __restrict__ b1,
                                               const void* __restrict__ w2,
                                               unsigned* __restrict__ y2b,
                                               const int* __restrict__ flag) {
    __shared__ float w2l[H1 * H2];
    __shared__ float b1l[H1];
    __shared__ float hbuf[512];
    const bool isf32 = (*flag != 0);
    int tid = threadIdx.x;
    for (int i = tid; i < H1 * H2; i += 256) w2l[i] = ldf(w2, i, isf32);
    if (tid < H1) b1l[tid] = ldf(b1, tid, isf32);
    __syncthreads();

    const int r = tid & 15;
    const int node = blockIdx.x * 16 + (tid >> 4);   // 31250*16 == 500000

    float a0 = 0.f, a1 = 0.f;
    const int beg = off[node], end = off[node + 1];
    int j = beg;
    for (; j + 4 <= end; j += 4) {
        int s0 = csr[j], s1 = csr[j + 1], s2 = csr[j + 2], s3 = csr[j + 3];
        unsigned u0 = y1b[(size_t)s0 * 16 + r];
        unsigned u1 = y1b[(size_t)s1 * 16 + r];
        unsigned u2 = y1b[(size_t)s2 * 16 + r];
        unsigned u3 = y1b[(size_t)s3 * 16 + r];
        a0 += __uint_as_float(u0 << 16) + __uint_as_float(u1 << 16)
            + __uint_as_float(u2 << 16) + __uint_as_float(u3 << 16);
        a1 += __uint_as_float(u0 & 0xffff0000u) + __uint_as_float(u1 & 0xffff0000u)
            + __uint_as_float(u2 & 0xffff0000u) + __uint_as_float(u3 & 0xffff0000u);
    }
    for (; j < end; ++j) {
        unsigned u = y1b[(size_t)csr[j] * 16 + r];
        a0 += __uint_as_float(u << 16);
        a1 += __uint_as_float(u & 0xffff0000u);
    }
    float sc = dinv[node];
    unsigned su = y1b[(size_t)node * 16 + r];        // self term (pre-scaled)
    a0 += __uint_as_float(su << 16);
    a1 += __uint_as_float(su & 0xffff0000u);
    float h0 = sc * a0 + b1l[2 * r];
    float h1 = sc * a1 + b1l[2 * r + 1];
    h0 = h0 > 0.f ? h0 : 0.f;
    h1 = h1 > 0.f ? h1 : 0.f;
    hbuf[tid * 2] = h0;
    hbuf[tid * 2 + 1] = h1;                          // same-wave readers only
    const float* hr = &hbuf[(tid & ~15) * 2];
    float a2 = 0.f;
#pragma unroll
    for (int k = 0; k < H1; ++k) a2 += hr[k] * w2l[k * H2 + r];
    a2 *= sc;
    int gwb = (tid & 63) & ~15;                      // wave-lane group base
    float v0 = __shfl(a2, (gwb + 2 * r) & 63, 64);
    float v1 = __shfl(a2, (gwb + 2 * r + 1) & 63, 64);
    if (r < 8) y2b[(size_t)node * 8 + r] = pack2bf(v0, v1);
}

// ---- pull layer 2: 8 lanes/node, ILP-4, fused relu+FC+log_softmax ----
__global__ __launch_bounds__(256) void k_pull2(const int* __restrict__ off,
                                               const int* __restrict__ csr,
                                               const unsigned* __restrict__ y2b,
                                               const float* __restrict__ dinv,
                                               const void* __restrict__ b2,
                                               const void* __restrict__ wfc,
                                               const void* __restrict__ bfc,
                                               void* __restrict__ out,
                                               const int* __restrict__ flag) {
    __shared__ float wl[H2 * 2];
    __shared__ float b2l[H2];
    __shared__ float bfl[2];
    const bool isf32 = (*flag != 0);
    int tid = threadIdx.x;
    if (tid < H2 * 2) wl[tid] = ldf(wfc, tid, isf32);
    if (tid < H2) b2l[tid] = ldf(b2, tid, isf32);
    if (tid < 2) bfl[tid] = ldf(bfc, tid, isf32);
    __syncthreads();

    const int r = tid & 7;
    const int node = blockIdx.x * 32 + (tid >> 3);   // 15625*32 == 500000

    float a0 = 0.f, a1 = 0.f;
    const int beg = off[node], end = off[node + 1];
    int j = beg;
    for (; j + 4 <= end; j += 4) {
        int s0 = csr[j], s1 = csr[j + 1], s2 = csr[j + 2], s3 = csr[j + 3];
        unsigned u0 = y2b[(size_t)s0 * 8 + r];
        unsigned u1 = y2b[(size_t)s1 * 8 + r];
        unsigned u2 = y2b[(size_t)s2 * 8 + r];
        unsigned u3 = y2b[(size_t)s3 * 8 + r];
        a0 += __uint_as_float(u0 << 16) + __uint_as_float(u1 << 16)
            + __uint_as_float(u2 << 16) + __uint_as_float(u3 << 16);
        a1 += __uint_as_float(u0 & 0xffff0000u) + __uint_as_float(u1 & 0xffff0000u)
            + __uint_as_float(u2 & 0xffff0000u) + __uint_as_float(u3 & 0xffff0000u);
    }
    for (; j < end; ++j) {
        unsigned u = y2b[(size_t)csr[j] * 8 + r];
        a0 += __uint_as_float(u << 16);
        a1 += __uint_as_float(u & 0xffff0000u);
    }
    float sc = dinv[node];
    unsigned su = y2b[(size_t)node * 8 + r];
    a0 += __uint_as_float(su << 16);
    a1 += __uint_as_float(su & 0xffff0000u);
    float h0 = sc * a0 + b2l[2 * r];
    float h1 = sc * a1 + b2l[2 * r + 1];
    h0 = h0 > 0.f ? h0 : 0.f;
    h1 = h1 > 0.f ? h1 : 0.f;
    float l0 = h0 * wl[4 * r]     + h1 * wl[4 * r + 2];
    float l1 = h0 * wl[4 * r + 1] + h1 * wl[4 * r + 3];
#pragma unroll
    for (int o = 4; o >= 1; o >>= 1) {
        l0 += __shfl_xor(l0, o, 8);
        l1 += __shfl_xor(l1, o, 8);
    }
    if (r == 0) {
        l0 += bfl[0];
        l1 += bfl[1];
        float mx = fmaxf(l0, l1);
        float lse = mx + logf(__expf(l0 - mx) + __expf(l1 - mx));
        if (isf32) {
            reinterpret_cast<float2*>(out)[node] = make_float2(l0 - lse, l1 - lse);
        } else {
            reinterpret_cast<unsigned*>(out)[node] =
                (unsigned)f2bf(l0 - lse) | ((unsigned)f2bf(l1 - lse) << 16);
        }
    }
}

extern "C" void kernel_launch(void* const* d_in, const int* in_sizes, int n_in,
                              void* d_out, int out_size, void* d_ws, size_t ws_size,
                              hipStream_t stream) {
    const void* x   = d_in[0];
    const int*  ei  = (const int*)d_in[1];
    const void* w1  = d_in[2];
    const void* b1  = d_in[3];
    const void* w2  = d_in[4];
    const void* b2  = d_in[5];
    const void* wfc = d_in[6];
    const void* bfc = d_in[7];
    const int* src = ei;
    const int* dst = ei + N_EDGES;

    // workspace (4B units), ~116 MB. csr overlays ebufA (dead after k_scatB).
    // flag@0 | dinv@64(500224) | fhist@500288(2048) | fbase@502336(2048)
    // acur@504384(64) | bcur@504448(2048) | off@506496(500288)
    // ebufA/csr@1006784(8M) | ebufB@9006784(8M)
    // y1b@17006784(8003584) | y2b@25010368(4001792)
    float*    ws    = (float*)d_ws;
    int*      flag  = (int*)ws;
    float*    dinv  = ws + 64;
    int*      fhist = (int*)(ws + 500288);
    int*      fbase = (int*)(ws + 502336);
    int*      acur  = (int*)(ws + 504384);
    int*      bcur  = (int*)(ws + 504448);
    int*      off   = (int*)(ws + 506496);
    unsigned* ebufA = (unsigned*)(ws + 1006784);
    int*      csr   = (int*)(ws + 1006784);     // reuses ebufA
    unsigned* ebufB = (unsigned*)(ws + 9006784);
    unsigned* y1b   = (unsigned*)(ws + 17006784);
    unsigned* y2b   = (unsigned*)(ws + 25010368);

    k_sniff<<<1, 64, 0, stream>>>((const unsigned int*)x, flag);
    hipMemsetAsync(fhist, 0, 2048 * sizeof(int), stream);
    k_bhist<<<256, 256, 0, stream>>>(dst, fhist);
    k_scanf<<<1, 256, 0, stream>>>(fhist, fbase, bcur, acur);
    k_scatA<<<977, 256, 0, stream>>>(src, dst, acur, ebufA);
    k_scatB<<<NCOARSE * 8, 256, 0, stream>>>(ebufA, fbase, bcur, ebufB);
    k_csr<<<NFINE, 256, 0, stream>>>(ebufB, fbase, csr, off, dinv);
    k_gemm1<<<NFINE, 256, 0, stream>>>(x, w1, dinv, y1b, flag);
    k_pull1<<<31250, 256, 0, stream>>>(off, csr, y1b, dinv, b1, w2, y2b, flag);
    k_pull2<<<15625, 256, 0, stream>>>(off, csr, y2b, dinv, b2, wfc, bfc, d_out, flag);
}